// Round 2
// baseline (607.103 us; speedup 1.0000x reference)
//
#include <hip/hip_runtime.h>

#define ZC     256     // channels (reduction dim)
#define KCODES 1024    // codebook size
#define BP     64      // points per block
#define BKC    128     // codes per chunk
#define CCH    32      // channels per LDS stage
#define AS_S   72      // A tile row stride (floats): 16B-aligned, bank-uniform
#define BS_S   132     // B tile row stride (floats): 16B-aligned
#define MARGIN 1e-4f   // top-2 gap below which we adjudicate with np-replicated math

// ---------------------------------------------------------------------------
// numpy pairwise_sum replication (n=128 block: 8 accumulators, unrolled by 8;
// n=256: lo128 + hi128). All ops unfused IEEE f32 (__fmul_rn/__fadd_rn).
// ---------------------------------------------------------------------------
__device__ __forceinline__ float np_pair128_sq(const float* __restrict__ a) {
    float r[8];
    #pragma unroll
    for (int j = 0; j < 8; ++j) r[j] = __fmul_rn(a[j], a[j]);
    #pragma unroll
    for (int i = 8; i < 128; i += 8)
        #pragma unroll
        for (int j = 0; j < 8; ++j) r[j] = __fadd_rn(r[j], __fmul_rn(a[i + j], a[i + j]));
    const float s01 = __fadd_rn(r[0], r[1]);
    const float s23 = __fadd_rn(r[2], r[3]);
    const float s45 = __fadd_rn(r[4], r[5]);
    const float s67 = __fadd_rn(r[6], r[7]);
    return __fadd_rn(__fadd_rn(s01, s23), __fadd_rn(s45, s67));
}
__device__ __forceinline__ float np_sum256_sq(const float* __restrict__ a) {
    return __fadd_rn(np_pair128_sq(a), np_pair128_sq(a + 128));
}

// ---------------------------------------------------------------------------
// Kernel 1: fused distance-GEMM + top-2 argmin.
// Block = 256 threads = 64 points x all 1024 codes (chunks of 128).
// Thread microtile: 4 points x 8 codes. Writes index (float). Points whose
// top-2 gap <= MARGIN are flagged via negative encoding for exact fixup.
// ---------------------------------------------------------------------------
__global__ __launch_bounds__(256)
void vq_argmin_kernel(const float* __restrict__ z, const float* __restrict__ emb,
                      float* __restrict__ out_idx)
{
    __shared__ float ens[KCODES];
    __shared__ float As[CCH * AS_S];
    __shared__ float Bs[CCH * BS_S];

    const int t    = threadIdx.x;
    const int lane = t & 63;
    const int wv   = t >> 6;

    // Phase 0: codebook squared norms (approx is fine here; margin absorbs it).
    for (int k = wv; k < KCODES; k += 4) {
        const float4 v = *reinterpret_cast<const float4*>(emb + (size_t)k * ZC + lane * 4);
        float s = v.x * v.x + v.y * v.y + v.z * v.z + v.w * v.w;
        #pragma unroll
        for (int m = 1; m < 64; m <<= 1) s += __shfl_xor(s, m);
        if (lane == 0) ens[k] = s;
    }
    __syncthreads();

    const int n0 = blockIdx.x * BP;
    const int b  = n0 >> 10;
    const int q0 = n0 & 1023;
    const float* zb = z + (size_t)b * (ZC * 1024) + q0;

    const int tx = t & 15;
    const int ty = t >> 4;

    float v1[4], v2[4];
    int   id1[4];
    #pragma unroll
    for (int i = 0; i < 4; ++i) { v1[i] = 3.4e38f; v2[i] = 3.4e38f; id1[i] = 0; }

    for (int k0 = 0; k0 < KCODES; k0 += BKC) {
        float acc[4][8];
        #pragma unroll
        for (int i = 0; i < 4; ++i)
            #pragma unroll
            for (int j = 0; j < 8; ++j) acc[i][j] = 0.f;

        for (int c0 = 0; c0 < ZC; c0 += CCH) {
            __syncthreads();
            {   // Stage A: z tile, 32 c-rows x 64 points.
                const int cl = t >> 3, w4 = t & 7;
                const float* src = zb + (size_t)(c0 + cl) * 1024 + w4 * 4;
                const float4 a0 = *reinterpret_cast<const float4*>(src);
                const float4 a1 = *reinterpret_cast<const float4*>(src + 32);
                float* dst = As + cl * AS_S + w4 * 4;
                *reinterpret_cast<float4*>(dst)      = a0;
                *reinterpret_cast<float4*>(dst + 32) = a1;
            }
            {   // Stage B: embedding tile transposed into Bs[c][k].
                const int kl = t >> 3, c4 = t & 7;
                #pragma unroll
                for (int kk = 0; kk < 4; ++kk) {
                    const int kidx = kl + kk * 32;
                    const float4 v = *reinterpret_cast<const float4*>(
                        emb + (size_t)(k0 + kidx) * ZC + c0 + c4 * 4);
                    Bs[(c4 * 4 + 0) * BS_S + kidx] = v.x;
                    Bs[(c4 * 4 + 1) * BS_S + kidx] = v.y;
                    Bs[(c4 * 4 + 2) * BS_S + kidx] = v.z;
                    Bs[(c4 * 4 + 3) * BS_S + kidx] = v.w;
                }
            }
            __syncthreads();

            #pragma unroll 8
            for (int c = 0; c < CCH; ++c) {
                const float4 a  = *reinterpret_cast<const float4*>(As + c * AS_S + ty * 4);
                const float4 b0 = *reinterpret_cast<const float4*>(Bs + c * BS_S + tx * 4);
                const float4 b1 = *reinterpret_cast<const float4*>(Bs + c * BS_S + 64 + tx * 4);
                const float av[4] = {a.x, a.y, a.z, a.w};
                const float bv[8] = {b0.x, b0.y, b0.z, b0.w, b1.x, b1.y, b1.z, b1.w};
                #pragma unroll
                for (int i = 0; i < 4; ++i)
                    #pragma unroll
                    for (int j = 0; j < 8; ++j)
                        acc[i][j] = fmaf(av[i], bv[j], acc[i][j]);
            }
        }

        // Chunk epilogue: s = ||e||^2 - 2*dot ; running top-2 (k ascending).
        #pragma unroll
        for (int j = 0; j < 8; ++j) {
            const int k = k0 + ((j < 4) ? (tx * 4 + j) : (64 + tx * 4 + (j - 4)));
            const float en = ens[k];
            #pragma unroll
            for (int i = 0; i < 4; ++i) {
                const float s = fmaf(-2.f, acc[i][j], en);
                if (s < v1[i])      { v2[i] = v1[i]; v1[i] = s; id1[i] = k; }
                else if (s < v2[i]) { v2[i] = s; }
            }
        }
    }

    // Cross-lane top-2 merge over the 16 tx-threads per point.
    #pragma unroll
    for (int i = 0; i < 4; ++i) {
        float v1l = v1[i]; int idl = id1[i]; float v2l = v2[i];
        #pragma unroll
        for (int m = 1; m < 16; m <<= 1) {
            const float ov1 = __shfl_xor(v1l, m);
            const int   oid = __shfl_xor(idl, m);
            const float ov2 = __shfl_xor(v2l, m);
            if (ov1 < v1l)      { v2l = fminf(v1l, ov2); v1l = ov1; idl = oid; }
            else if (ov1 > v1l) { v2l = fminf(v2l, ov1); }
            else                { v2l = (oid != idl) ? v1l : fminf(v2l, ov2);
                                  idl = (oid < idl) ? oid : idl; }
        }
        if (tx == 0) {
            const bool flag = (v2l - v1l) <= MARGIN;
            out_idx[n0 + ty * 4 + i] = flag ? (-1.0f - (float)idl) : (float)idl;
        }
    }
}

// ---------------------------------------------------------------------------
// Kernel 1b: exact adjudication of flagged points, replicating numpy f32:
// d = fl32( fl32(znorm + enorm) - fl32(2 * dot) ), znorm/enorm via numpy
// pairwise order, dot in f64 (correctly rounded). First-min tie-break.
// ---------------------------------------------------------------------------
__global__ __launch_bounds__(256)
void vq_fixup_kernel(const float* __restrict__ z, const float* __restrict__ emb,
                     float* __restrict__ idxf)
{
    __shared__ int   list[64];
    __shared__ int   cnt;
    __shared__ float zs[ZC];
    __shared__ float redv[4];
    __shared__ int   redi[4];

    const int t  = threadIdx.x;
    const int n0 = blockIdx.x * 64;

    if (t == 0) cnt = 0;
    __syncthreads();
    if (t < 64) {
        if (idxf[n0 + t] < 0.f) { const int p = atomicAdd(&cnt, 1); list[p] = t; }
    }
    __syncthreads();
    const int C = cnt;

    for (int li = 0; li < C; ++li) {
        const int n = n0 + list[li];
        const int b = n >> 10, q = n & 1023;
        zs[t] = z[(size_t)b * (ZC * 1024) + (size_t)t * 1024 + q];
        __syncthreads();

        const float zn = np_sum256_sq(zs);   // redundant per-thread (LDS broadcast)

        float best = 3.4e38f; int bestk = 0;
        #pragma unroll
        for (int j = 0; j < 4; ++j) {
            const int k = t * 4 + j;
            const float* er = emb + (size_t)k * ZC;
            const float en = np_sum256_sq(er);
            double dd = 0.0;
            for (int c = 0; c < ZC; ++c) dd = fma((double)er[c], (double)zs[c], dd);
            const float t2 = (float)dd;
            const float d  = __fsub_rn(__fadd_rn(zn, en), __fmul_rn(2.0f, t2));
            if (d < best) { best = d; bestk = k; }   // k ascending -> first-min
        }
        #pragma unroll
        for (int m = 1; m < 64; m <<= 1) {
            const float ov = __shfl_xor(best, m);
            const int   oi = __shfl_xor(bestk, m);
            if (ov < best || (ov == best && oi < bestk)) { best = ov; bestk = oi; }
        }
        if ((t & 63) == 0) { redv[t >> 6] = best; redi[t >> 6] = bestk; }
        __syncthreads();
        if (t == 0) {
            float bv = redv[0]; int bk = redi[0];
            #pragma unroll
            for (int w = 1; w < 4; ++w)
                if (redv[w] < bv || (redv[w] == bv && redi[w] < bk)) { bv = redv[w]; bk = redi[w]; }
            idxf[n] = (float)bk;
        }
        __syncthreads();
    }
}

// ---------------------------------------------------------------------------
// Kernel 2: outputs. One block per (b,h): 32 w x 256 c tile.
// ---------------------------------------------------------------------------
__global__ __launch_bounds__(256)
void vq_outputs_kernel(const float* __restrict__ z, const float* __restrict__ emb,
                       const float* __restrict__ idxf,
                       float* __restrict__ out_q, float* __restrict__ out_loss)
{
    __shared__ float zts[32 * 257];
    __shared__ int   ids[32];

    const int t  = threadIdx.x;
    const int bh = blockIdx.x;
    const int b  = bh >> 5, h = bh & 31;
    const int n0 = bh * 32;

    if (t < 32) ids[t] = (int)idxf[n0 + t];
    __syncthreads();

    const size_t zbase = (size_t)b * (ZC * 1024) + h * 32;

    for (int rep = 0; rep < 32; ++rep) {
        const int flat = rep * 256 + t;
        const int c = flat >> 5;
        const int w = flat & 31;
        const size_t ga = zbase + (size_t)c * 1024 + w;
        const float zv = z[ga];
        zts[w * 257 + c] = zv;
        out_q[ga] = emb[(size_t)ids[w] * ZC + c];
    }
    __syncthreads();

    for (int rep = 0; rep < 32; ++rep) {
        const float e = emb[(size_t)ids[rep] * ZC + t];
        const float d = e - zts[rep * 257 + t];
        out_loss[(size_t)(n0 + rep) * ZC + t] = 1.25f * d * d;
    }
}

extern "C" void kernel_launch(void* const* d_in, const int* in_sizes, int n_in,
                              void* d_out, int out_size, void* d_ws, size_t ws_size,
                              hipStream_t stream)
{
    const float* z   = (const float*)d_in[0];   // [32,256,32,32]
    const float* emb = (const float*)d_in[1];   // [1024,256]
    float* out      = (float*)d_out;
    float* out_q    = out;                       // 8388608
    float* out_loss = out + 8388608;             // 8388608
    float* out_idx  = out + 16777216;            // 32768

    vq_argmin_kernel <<<32768 / BP, 256, 0, stream>>>(z, emb, out_idx);
    vq_fixup_kernel  <<<512,        256, 0, stream>>>(z, emb, out_idx);
    vq_outputs_kernel<<<1024,       256, 0, stream>>>(z, emb, out_idx, out_q, out_loss);
}

// Round 5
// 425.019 us; speedup vs baseline: 1.4284x; 1.4284x over previous
//
#include <hip/hip_runtime.h>

#define ZC     256
#define KCODES 1024
#define MARGIN 1e-4f
#define AS_S   72      // LDS row stride in bf16 (64 data + 8 pad): 16B-aligned, 2-way banks

typedef __attribute__((ext_vector_type(4))) float f32x4;
typedef __attribute__((ext_vector_type(8))) short s16x8;
typedef unsigned int u32t;

__device__ __forceinline__ unsigned short bf16_rn(float x) {
    union { float f; u32t u; } v; v.f = x;
    return (unsigned short)((v.u + 0x7FFFu + ((v.u >> 16) & 1u)) >> 16);
}
__device__ __forceinline__ float bf16_f(unsigned short h) {
    union { u32t u; float f; } v; v.u = ((u32t)h) << 16; return v.f;
}

// ---------------------------------------------------------------------------
// prep_z: z fp32 [32,256,32,32] -> A' bf16 LINEAR [8 kblk][32768 pt][64],
// kblk 0-3 = hi (c 0..255), kblk 4-7 = lo residual.
// ---------------------------------------------------------------------------
__global__ __launch_bounds__(256)
void vq_prep_z(const float* __restrict__ z, unsigned short* __restrict__ Ab)
{
    const int t = threadIdx.x, blk = blockIdx.x;
    const int pt = (blk >> 3) * 64 + (t & 63);
    const int c0 = (blk & 7) * 32 + (t >> 6) * 8;
    const int b = pt >> 10, hw = pt & 1023;
    const float* zp = z + (size_t)b * (ZC * 1024) + (size_t)c0 * 1024 + hw;

    unsigned short hi[8], lo[8];
    #pragma unroll
    for (int j = 0; j < 8; ++j) {
        const float v = zp[(size_t)j * 1024];
        const unsigned short h = bf16_rn(v);
        hi[j] = h; lo[j] = bf16_rn(v - bf16_f(h));
    }
    uint4 ph, pl;
    ph.x = (u32t)hi[0] | ((u32t)hi[1] << 16); ph.y = (u32t)hi[2] | ((u32t)hi[3] << 16);
    ph.z = (u32t)hi[4] | ((u32t)hi[5] << 16); ph.w = (u32t)hi[6] | ((u32t)hi[7] << 16);
    pl.x = (u32t)lo[0] | ((u32t)lo[1] << 16); pl.y = (u32t)lo[2] | ((u32t)lo[3] << 16);
    pl.z = (u32t)lo[4] | ((u32t)lo[5] << 16); pl.w = (u32t)lo[6] | ((u32t)lo[7] << 16);

    const size_t kbH = (size_t)(c0 >> 6), kbL = kbH + 4;
    const size_t base = (size_t)pt * 64 + (c0 & 63);
    *reinterpret_cast<uint4*>(Ab + kbH * (32768ull * 64) + base) = ph;
    *reinterpret_cast<uint4*>(Ab + kbL * (32768ull * 64) + base) = pl;
}

// ---------------------------------------------------------------------------
// prep_e: emb fp32 [1024,256] -> B' bf16 LINEAR [8 kblk][1024 code][64].
// ---------------------------------------------------------------------------
__global__ __launch_bounds__(256)
void vq_prep_e(const float* __restrict__ emb, unsigned short* __restrict__ Bb)
{
    const int t = threadIdx.x, blk = blockIdx.x;
    const int code = (blk >> 3) * 64 + (t & 63);
    const int c0 = (blk & 7) * 32 + (t >> 6) * 8;
    const float* ep = emb + (size_t)code * ZC + c0;

    unsigned short hi[8], lo[8];
    #pragma unroll
    for (int j = 0; j < 8; ++j) {
        const float v = ep[j];
        const unsigned short h = bf16_rn(v);
        hi[j] = h; lo[j] = bf16_rn(v - bf16_f(h));
    }
    uint4 ph, pl;
    ph.x = (u32t)hi[0] | ((u32t)hi[1] << 16); ph.y = (u32t)hi[2] | ((u32t)hi[3] << 16);
    ph.z = (u32t)hi[4] | ((u32t)hi[5] << 16); ph.w = (u32t)hi[6] | ((u32t)hi[7] << 16);
    pl.x = (u32t)lo[0] | ((u32t)lo[1] << 16); pl.y = (u32t)lo[2] | ((u32t)lo[3] << 16);
    pl.z = (u32t)lo[4] | ((u32t)lo[5] << 16); pl.w = (u32t)lo[6] | ((u32t)lo[7] << 16);

    const size_t kbH = (size_t)(c0 >> 6), kbL = kbH + 4;
    const size_t base = (size_t)code * 64 + (c0 & 63);
    *reinterpret_cast<uint4*>(Bb + kbH * (1024ull * 64) + base) = ph;
    *reinterpret_cast<uint4*>(Bb + kbL * (1024ull * 64) + base) = pl;
}

// ---------------------------------------------------------------------------
// ens: codebook squared norms (fp32) -> ens_g[1024].
// ---------------------------------------------------------------------------
__global__ __launch_bounds__(256)
void vq_ens(const float* __restrict__ emb, float* __restrict__ ens_g)
{
    const int t = threadIdx.x, lane = t & 63, w = t >> 6;
    for (int rep = 0; rep < 16; ++rep) {
        const int k = blockIdx.x * 64 + rep * 4 + w;
        const float4 v = *reinterpret_cast<const float4*>(emb + (size_t)k * ZC + lane * 4);
        float s = v.x * v.x + v.y * v.y + v.z * v.z + v.w * v.w;
        #pragma unroll
        for (int m = 1; m < 64; m <<= 1) s += __shfl_xor(s, m);
        if (lane == 0) ens_g[k] = s;
    }
}

// ---------------------------------------------------------------------------
// GEMM+argmin: 256 thr = 4 waves, tile 64 pts x 128 codes/ct, 8 cts, 12 k x 64.
// Wave wv owns codes wv*32..wv*32+31 of each code-tile; 4x1 m-frags x 2 n-frags.
// Ends with in-wave 16-lane merge + CROSS-WAVE merge via LDS (the round-3/4 bug).
// ---------------------------------------------------------------------------
__global__ __launch_bounds__(256, 2)
void vq_gemm_argmin(const unsigned short* __restrict__ Ab,
                    const unsigned short* __restrict__ Bb,
                    const float* __restrict__ ens_g, float* __restrict__ out_idx)
{
    __shared__ unsigned short As[64 * AS_S];    // 9,216 B (reused for merge)
    __shared__ unsigned short Bs[128 * AS_S];   // 18,432 B

    const int t = threadIdx.x;
    const int lane = t & 63, wv = t >> 6;        // wv = code-column wave index
    const int col = lane & 15, kg = lane >> 4;
    const int pt0 = blockIdx.x * 64;

    int aoff[4][2], boff[2][2];                  // offsets in shorts
    #pragma unroll
    for (int m = 0; m < 4; ++m)
        #pragma unroll
        for (int s = 0; s < 2; ++s)
            aoff[m][s] = (m * 16 + col) * AS_S + s * 32 + kg * 8;
    #pragma unroll
    for (int n = 0; n < 2; ++n)
        #pragma unroll
        for (int s = 0; s < 2; ++s)
            boff[n][s] = (wv * 32 + n * 16 + col) * AS_S + s * 32 + kg * 8;

    f32x4 acc[4][2];
    #pragma unroll
    for (int m = 0; m < 4; ++m)
        #pragma unroll
        for (int n = 0; n < 2; ++n) acc[m][n] = (f32x4){0.f, 0.f, 0.f, 0.f};

    float v1[16], v2[16]; int id1[16];
    #pragma unroll
    for (int i = 0; i < 16; ++i) { v1[i] = 3.4e38f; v2[i] = 3.4e38f; id1[i] = 0; }

    for (int ct = 0; ct < 8; ++ct) {
        for (int ks = 0; ks < 12; ++ks) {
            const int kbA = (((ks >> 2) == 1) ? 4 : 0) + (ks & 3);
            const int kbB = (((ks >> 2) == 2) ? 4 : 0) + (ks & 3);
            const unsigned short* aS = Ab + (size_t)kbA * (32768ull * 64) + (size_t)pt0 * 64;
            const unsigned short* bS = Bb + (size_t)kbB * (1024ull * 64)  + (size_t)ct * (128 * 64);

            __syncthreads();   // prior k-step's LDS reads complete
            #pragma unroll
            for (int q = 0; q < 2; ++q) {       // A: 64 rows x 64 shorts
                const int gid = q * 256 + t, row = gid >> 3, gr = gid & 7;
                *reinterpret_cast<uint4*>(As + row * AS_S + gr * 8) =
                    *reinterpret_cast<const uint4*>(aS + row * 64 + gr * 8);
            }
            #pragma unroll
            for (int q = 0; q < 4; ++q) {       // B: 128 rows x 64 shorts
                const int gid = q * 256 + t, row = gid >> 3, gr = gid & 7;
                *reinterpret_cast<uint4*>(Bs + row * AS_S + gr * 8) =
                    *reinterpret_cast<const uint4*>(bS + row * 64 + gr * 8);
            }
            __syncthreads();

            s16x8 af[4][2], bf[2][2];
            #pragma unroll
            for (int m = 0; m < 4; ++m)
                #pragma unroll
                for (int s = 0; s < 2; ++s)
                    af[m][s] = *reinterpret_cast<const s16x8*>(As + aoff[m][s]);
            #pragma unroll
            for (int n = 0; n < 2; ++n)
                #pragma unroll
                for (int s = 0; s < 2; ++s)
                    bf[n][s] = *reinterpret_cast<const s16x8*>(Bs + boff[n][s]);
            #pragma unroll
            for (int m = 0; m < 4; ++m)
                #pragma unroll
                for (int n = 0; n < 2; ++n) {
                    acc[m][n] = __builtin_amdgcn_mfma_f32_16x16x32_bf16(af[m][0], bf[n][0], acc[m][n], 0, 0, 0);
                    acc[m][n] = __builtin_amdgcn_mfma_f32_16x16x32_bf16(af[m][1], bf[n][1], acc[m][n], 0, 0, 0);
                }

            if (ks == 11) {   // code-tile epilogue: top-2 update (codes ascending), reset acc
                #pragma unroll
                for (int n = 0; n < 2; ++n) {
                    const int code = ct * 128 + wv * 32 + n * 16 + col;
                    const float en = ens_g[code];
                    #pragma unroll
                    for (int m = 0; m < 4; ++m)
                        #pragma unroll
                        for (int j = 0; j < 4; ++j) {
                            const float sc = fmaf(-2.f, acc[m][n][j], en);
                            const int sl = m * 4 + j;
                            if (sc < v1[sl]) { v2[sl] = v1[sl]; v1[sl] = sc; id1[sl] = code; }
                            else if (sc < v2[sl]) { v2[sl] = sc; }
                            acc[m][n][j] = 0.f;
                        }
                }
            }
        }
    }

    // ---- stage 1: in-wave top-2 merge over the 16 col-lanes per kg group ----
    float w1[16], w2[16]; int wid[16];
    #pragma unroll
    for (int sl = 0; sl < 16; ++sl) {
        float a1 = v1[sl]; int ai = id1[sl]; float a2 = v2[sl];
        #pragma unroll
        for (int mk = 1; mk < 16; mk <<= 1) {
            const float o1 = __shfl_xor(a1, mk);
            const int   oi = __shfl_xor(ai, mk);
            const float o2 = __shfl_xor(a2, mk);
            if (o1 < a1)      { a2 = fminf(a1, o2); a1 = o1; ai = oi; }
            else if (o1 > a1) { a2 = fminf(a2, o1); }
            else              { a2 = (oi != ai) ? a1 : fminf(a2, o2); ai = (oi < ai) ? oi : ai; }
        }
        w1[sl] = a1; w2[sl] = a2; wid[sl] = ai;
    }

    // ---- stage 2: cross-wave merge via LDS (this was missing in r3/r4) ----
    __syncthreads();                 // all LDS reads of the GEMM are done
    float* mv1 = reinterpret_cast<float*>(As);          // [4 wv][64 pt]
    float* mv2 = mv1 + 256;                             // [4][64]
    int*   mid = reinterpret_cast<int*>(mv2 + 256);     // [4][64]
    if (col == 0) {
        #pragma unroll
        for (int sl = 0; sl < 16; ++sl) {
            const int m = sl >> 2, j = sl & 3;
            const int p = m * 16 + kg * 4 + j;          // 0..63
            mv1[wv * 64 + p] = w1[sl];
            mv2[wv * 64 + p] = w2[sl];
            mid[wv * 64 + p] = wid[sl];
        }
    }
    __syncthreads();
    if (t < 64) {
        float a1 = mv1[t], a2 = mv2[t]; int ai = mid[t];
        #pragma unroll
        for (int w = 1; w < 4; ++w) {
            const float b1 = mv1[w * 64 + t], b2 = mv2[w * 64 + t];
            const int   bi = mid[w * 64 + t];
            if (b1 < a1)      { a2 = fminf(a1, b2); a1 = b1; ai = bi; }
            else if (b1 > a1) { a2 = fminf(a2, b1); }
            else              { a2 = a1; ai = (bi < ai) ? bi : ai; }
        }
        out_idx[pt0 + t] = ((a2 - a1) <= MARGIN) ? (-1.0f - (float)ai) : (float)ai;
    }
}

// ---------------------------------------------------------------------------
// numpy pairwise-sum replication + fixup (verified round 2, unchanged).
// ---------------------------------------------------------------------------
__device__ __forceinline__ float np_pair128_sq(const float* __restrict__ a) {
    float r[8];
    #pragma unroll
    for (int j = 0; j < 8; ++j) r[j] = __fmul_rn(a[j], a[j]);
    #pragma unroll
    for (int i = 8; i < 128; i += 8)
        #pragma unroll
        for (int j = 0; j < 8; ++j) r[j] = __fadd_rn(r[j], __fmul_rn(a[i + j], a[i + j]));
    const float s01 = __fadd_rn(r[0], r[1]);
    const float s23 = __fadd_rn(r[2], r[3]);
    const float s45 = __fadd_rn(r[4], r[5]);
    const float s67 = __fadd_rn(r[6], r[7]);
    return __fadd_rn(__fadd_rn(s01, s23), __fadd_rn(s45, s67));
}
__device__ __forceinline__ float np_sum256_sq(const float* __restrict__ a) {
    return __fadd_rn(np_pair128_sq(a), np_pair128_sq(a + 128));
}

__global__ __launch_bounds__(256)
void vq_fixup_kernel(const float* __restrict__ z, const float* __restrict__ emb,
                     float* __restrict__ idxf)
{
    __shared__ int   list[64];
    __shared__ int   cnt;
    __shared__ float zs[ZC];
    __shared__ float redv[4];
    __shared__ int   redi[4];

    const int t  = threadIdx.x;
    const int n0 = blockIdx.x * 64;

    if (t == 0) cnt = 0;
    __syncthreads();
    if (t < 64) {
        if (idxf[n0 + t] < 0.f) { const int p = atomicAdd(&cnt, 1); list[p] = t; }
    }
    __syncthreads();
    const int C = cnt;

    for (int li = 0; li < C; ++li) {
        const int n = n0 + list[li];
        const int b = n >> 10, q = n & 1023;
        zs[t] = z[(size_t)b * (ZC * 1024) + (size_t)t * 1024 + q];
        __syncthreads();

        const float zn = np_sum256_sq(zs);

        float best = 3.4e38f; int bestk = 0;
        #pragma unroll
        for (int j = 0; j < 4; ++j) {
            const int k = t * 4 + j;
            const float* er = emb + (size_t)k * ZC;
            const float en = np_sum256_sq(er);
            double dd = 0.0;
            for (int c = 0; c < ZC; ++c) dd = fma((double)er[c], (double)zs[c], dd);
            const float t2 = (float)dd;
            const float d  = __fsub_rn(__fadd_rn(zn, en), __fmul_rn(2.0f, t2));
            if (d < best) { best = d; bestk = k; }
        }
        #pragma unroll
        for (int m = 1; m < 64; m <<= 1) {
            const float ov = __shfl_xor(best, m);
            const int   oi = __shfl_xor(bestk, m);
            if (ov < best || (ov == best && oi < bestk)) { best = ov; bestk = oi; }
        }
        if ((t & 63) == 0) { redv[t >> 6] = best; redi[t >> 6] = bestk; }
        __syncthreads();
        if (t == 0) {
            float bv = redv[0]; int bk = redi[0];
            #pragma unroll
            for (int ww = 1; ww < 4; ++ww)
                if (redv[ww] < bv || (redv[ww] == bv && redi[ww] < bk)) { bv = redv[ww]; bk = redi[ww]; }
            idxf[n] = (float)bk;
        }
        __syncthreads();
    }
}

// ---------------------------------------------------------------------------
// outputs (verified round 2, unchanged) — overwrites the scratch regions.
// ---------------------------------------------------------------------------
__global__ __launch_bounds__(256)
void vq_outputs_kernel(const float* __restrict__ z, const float* __restrict__ emb,
                       const float* __restrict__ idxf,
                       float* __restrict__ out_q, float* __restrict__ out_loss)
{
    __shared__ float zts[32 * 257];
    __shared__ int   ids[32];

    const int t  = threadIdx.x;
    const int bh = blockIdx.x;
    const int b  = bh >> 5, h = bh & 31;
    const int n0 = bh * 32;

    if (t < 32) ids[t] = (int)idxf[n0 + t];
    __syncthreads();

    const size_t zbase = (size_t)b * (ZC * 1024) + h * 32;

    for (int rep = 0; rep < 32; ++rep) {
        const int flat = rep * 256 + t;
        const int c = flat >> 5;
        const int ww = flat & 31;
        const size_t ga = zbase + (size_t)c * 1024 + ww;
        const float zv = z[ga];
        zts[ww * 257 + c] = zv;
        out_q[ga] = emb[(size_t)ids[ww] * ZC + c];
    }
    __syncthreads();

    for (int rep = 0; rep < 32; ++rep) {
        const float e = emb[(size_t)ids[rep] * ZC + t];
        const float d = e - zts[rep * 257 + t];
        out_loss[(size_t)(n0 + rep) * ZC + t] = 1.25f * d * d;
    }
}

extern "C" void kernel_launch(void* const* d_in, const int* in_sizes, int n_in,
                              void* d_out, int out_size, void* d_ws, size_t ws_size,
                              hipStream_t stream)
{
    const float* z   = (const float*)d_in[0];   // [32,256,32,32]
    const float* emb = (const float*)d_in[1];   // [1024,256]
    float* out      = (float*)d_out;
    float* out_q    = out;                       // 8388608 floats (33,554,432 B)
    float* out_loss = out + 8388608;             // 8388608 floats
    float* out_idx  = out + 16777216;            // 32768 floats

    // scratch carved from output regions (fully overwritten by final kernels):
    unsigned short* Ab = (unsigned short*)d_out;                          // 32 MiB == out_q
    unsigned short* Bb = (unsigned short*)((char*)d_out + 33554432);      // 1 MiB head of out_loss
    float* ensg = (float*)((char*)d_out + 33554432 + 1048576);            // 4 KiB

    vq_prep_z        <<<4096, 256, 0, stream>>>(z, Ab);
    vq_prep_e        <<<128,  256, 0, stream>>>(emb, Bb);
    vq_ens           <<<16,   256, 0, stream>>>(emb, ensg);
    vq_gemm_argmin   <<<512,  256, 0, stream>>>(Ab, Bb, ensg, out_idx);
    vq_fixup_kernel  <<<512,  256, 0, stream>>>(z, emb, out_idx);
    vq_outputs_kernel<<<1024, 256, 0, stream>>>(z, emb, out_idx, out_q, out_loss);
}

// Round 6
// 281.124 us; speedup vs baseline: 2.1596x; 1.5119x over previous
//
#include <hip/hip_runtime.h>

#define ZC     256
#define KCODES 1024
#define MARGIN 1e-4f
#define AS_S   72      // LDS row stride in bf16 (64 data + 8 pad): 16B-aligned, 2-way banks

typedef __attribute__((ext_vector_type(4))) float f32x4;
typedef __attribute__((ext_vector_type(8))) short s16x8;
typedef unsigned int u32t;

__device__ __forceinline__ unsigned short bf16_rn(float x) {
    union { float f; u32t u; } v; v.f = x;
    return (unsigned short)((v.u + 0x7FFFu + ((v.u >> 16) & 1u)) >> 16);
}
__device__ __forceinline__ float bf16_f(unsigned short h) {
    union { u32t u; float f; } v; v.u = ((u32t)h) << 16; return v.f;
}

// ---------------------------------------------------------------------------
// prep_z: z fp32 [32,256,32,32] -> A' bf16 LINEAR [8 kblk][32768 pt][64],
// kblk 0-3 = hi (c 0..255), kblk 4-7 = lo residual.
// ---------------------------------------------------------------------------
__global__ __launch_bounds__(256)
void vq_prep_z(const float* __restrict__ z, unsigned short* __restrict__ Ab)
{
    const int t = threadIdx.x, blk = blockIdx.x;
    const int pt = (blk >> 3) * 64 + (t & 63);
    const int c0 = (blk & 7) * 32 + (t >> 6) * 8;
    const int b = pt >> 10, hw = pt & 1023;
    const float* zp = z + (size_t)b * (ZC * 1024) + (size_t)c0 * 1024 + hw;

    unsigned short hi[8], lo[8];
    #pragma unroll
    for (int j = 0; j < 8; ++j) {
        const float v = zp[(size_t)j * 1024];
        const unsigned short h = bf16_rn(v);
        hi[j] = h; lo[j] = bf16_rn(v - bf16_f(h));
    }
    uint4 ph, pl;
    ph.x = (u32t)hi[0] | ((u32t)hi[1] << 16); ph.y = (u32t)hi[2] | ((u32t)hi[3] << 16);
    ph.z = (u32t)hi[4] | ((u32t)hi[5] << 16); ph.w = (u32t)hi[6] | ((u32t)hi[7] << 16);
    pl.x = (u32t)lo[0] | ((u32t)lo[1] << 16); pl.y = (u32t)lo[2] | ((u32t)lo[3] << 16);
    pl.z = (u32t)lo[4] | ((u32t)lo[5] << 16); pl.w = (u32t)lo[6] | ((u32t)lo[7] << 16);

    const size_t kbH = (size_t)(c0 >> 6), kbL = kbH + 4;
    const size_t base = (size_t)pt * 64 + (c0 & 63);
    *reinterpret_cast<uint4*>(Ab + kbH * (32768ull * 64) + base) = ph;
    *reinterpret_cast<uint4*>(Ab + kbL * (32768ull * 64) + base) = pl;
}

// ---------------------------------------------------------------------------
// prep_e: emb fp32 [1024,256] -> B' bf16 LINEAR [8 kblk][1024 code][64].
// ---------------------------------------------------------------------------
__global__ __launch_bounds__(256)
void vq_prep_e(const float* __restrict__ emb, unsigned short* __restrict__ Bb)
{
    const int t = threadIdx.x, blk = blockIdx.x;
    const int code = (blk >> 3) * 64 + (t & 63);
    const int c0 = (blk & 7) * 32 + (t >> 6) * 8;
    const float* ep = emb + (size_t)code * ZC + c0;

    unsigned short hi[8], lo[8];
    #pragma unroll
    for (int j = 0; j < 8; ++j) {
        const float v = ep[j];
        const unsigned short h = bf16_rn(v);
        hi[j] = h; lo[j] = bf16_rn(v - bf16_f(h));
    }
    uint4 ph, pl;
    ph.x = (u32t)hi[0] | ((u32t)hi[1] << 16); ph.y = (u32t)hi[2] | ((u32t)hi[3] << 16);
    ph.z = (u32t)hi[4] | ((u32t)hi[5] << 16); ph.w = (u32t)hi[6] | ((u32t)hi[7] << 16);
    pl.x = (u32t)lo[0] | ((u32t)lo[1] << 16); pl.y = (u32t)lo[2] | ((u32t)lo[3] << 16);
    pl.z = (u32t)lo[4] | ((u32t)lo[5] << 16); pl.w = (u32t)lo[6] | ((u32t)lo[7] << 16);

    const size_t kbH = (size_t)(c0 >> 6), kbL = kbH + 4;
    const size_t base = (size_t)code * 64 + (c0 & 63);
    *reinterpret_cast<uint4*>(Bb + kbH * (1024ull * 64) + base) = ph;
    *reinterpret_cast<uint4*>(Bb + kbL * (1024ull * 64) + base) = pl;
}

// ---------------------------------------------------------------------------
// ens: codebook squared norms (fp32) -> ens_g[1024]. Also zeroes the fixup
// worklist counter (runs before the GEMM every launch -> deterministic).
// ---------------------------------------------------------------------------
__global__ __launch_bounds__(256)
void vq_ens(const float* __restrict__ emb, float* __restrict__ ens_g,
            int* __restrict__ cnt)
{
    if (blockIdx.x == 0 && threadIdx.x == 0) *cnt = 0;
    const int t = threadIdx.x, lane = t & 63, w = t >> 6;
    for (int rep = 0; rep < 16; ++rep) {
        const int k = blockIdx.x * 64 + rep * 4 + w;
        const float4 v = *reinterpret_cast<const float4*>(emb + (size_t)k * ZC + lane * 4);
        float s = v.x * v.x + v.y * v.y + v.z * v.z + v.w * v.w;
        #pragma unroll
        for (int m = 1; m < 64; m <<= 1) s += __shfl_xor(s, m);
        if (lane == 0) ens_g[k] = s;
    }
}

// ---------------------------------------------------------------------------
// GEMM+argmin (verified round 5, unchanged): 4 waves, 64 pts x 128 codes/ct,
// in-wave 16-lane merge + cross-wave LDS merge.
// ---------------------------------------------------------------------------
__global__ __launch_bounds__(256, 2)
void vq_gemm_argmin(const unsigned short* __restrict__ Ab,
                    const unsigned short* __restrict__ Bb,
                    const float* __restrict__ ens_g, float* __restrict__ out_idx)
{
    __shared__ unsigned short As[64 * AS_S];
    __shared__ unsigned short Bs[128 * AS_S];

    const int t = threadIdx.x;
    const int lane = t & 63, wv = t >> 6;
    const int col = lane & 15, kg = lane >> 4;
    const int pt0 = blockIdx.x * 64;

    int aoff[4][2], boff[2][2];
    #pragma unroll
    for (int m = 0; m < 4; ++m)
        #pragma unroll
        for (int s = 0; s < 2; ++s)
            aoff[m][s] = (m * 16 + col) * AS_S + s * 32 + kg * 8;
    #pragma unroll
    for (int n = 0; n < 2; ++n)
        #pragma unroll
        for (int s = 0; s < 2; ++s)
            boff[n][s] = (wv * 32 + n * 16 + col) * AS_S + s * 32 + kg * 8;

    f32x4 acc[4][2];
    #pragma unroll
    for (int m = 0; m < 4; ++m)
        #pragma unroll
        for (int n = 0; n < 2; ++n) acc[m][n] = (f32x4){0.f, 0.f, 0.f, 0.f};

    float v1[16], v2[16]; int id1[16];
    #pragma unroll
    for (int i = 0; i < 16; ++i) { v1[i] = 3.4e38f; v2[i] = 3.4e38f; id1[i] = 0; }

    for (int ct = 0; ct < 8; ++ct) {
        for (int ks = 0; ks < 12; ++ks) {
            const int kbA = (((ks >> 2) == 1) ? 4 : 0) + (ks & 3);
            const int kbB = (((ks >> 2) == 2) ? 4 : 0) + (ks & 3);
            const unsigned short* aS = Ab + (size_t)kbA * (32768ull * 64) + (size_t)pt0 * 64;
            const unsigned short* bS = Bb + (size_t)kbB * (1024ull * 64)  + (size_t)ct * (128 * 64);

            __syncthreads();
            #pragma unroll
            for (int q = 0; q < 2; ++q) {
                const int gid = q * 256 + t, row = gid >> 3, gr = gid & 7;
                *reinterpret_cast<uint4*>(As + row * AS_S + gr * 8) =
                    *reinterpret_cast<const uint4*>(aS + row * 64 + gr * 8);
            }
            #pragma unroll
            for (int q = 0; q < 4; ++q) {
                const int gid = q * 256 + t, row = gid >> 3, gr = gid & 7;
                *reinterpret_cast<uint4*>(Bs + row * AS_S + gr * 8) =
                    *reinterpret_cast<const uint4*>(bS + row * 64 + gr * 8);
            }
            __syncthreads();

            s16x8 af[4][2], bf[2][2];
            #pragma unroll
            for (int m = 0; m < 4; ++m)
                #pragma unroll
                for (int s = 0; s < 2; ++s)
                    af[m][s] = *reinterpret_cast<const s16x8*>(As + aoff[m][s]);
            #pragma unroll
            for (int n = 0; n < 2; ++n)
                #pragma unroll
                for (int s = 0; s < 2; ++s)
                    bf[n][s] = *reinterpret_cast<const s16x8*>(Bs + boff[n][s]);
            #pragma unroll
            for (int m = 0; m < 4; ++m)
                #pragma unroll
                for (int n = 0; n < 2; ++n) {
                    acc[m][n] = __builtin_amdgcn_mfma_f32_16x16x32_bf16(af[m][0], bf[n][0], acc[m][n], 0, 0, 0);
                    acc[m][n] = __builtin_amdgcn_mfma_f32_16x16x32_bf16(af[m][1], bf[n][1], acc[m][n], 0, 0, 0);
                }

            if (ks == 11) {
                #pragma unroll
                for (int n = 0; n < 2; ++n) {
                    const int code = ct * 128 + wv * 32 + n * 16 + col;
                    const float en = ens_g[code];
                    #pragma unroll
                    for (int m = 0; m < 4; ++m)
                        #pragma unroll
                        for (int j = 0; j < 4; ++j) {
                            const float sc = fmaf(-2.f, acc[m][n][j], en);
                            const int sl = m * 4 + j;
                            if (sc < v1[sl]) { v2[sl] = v1[sl]; v1[sl] = sc; id1[sl] = code; }
                            else if (sc < v2[sl]) { v2[sl] = sc; }
                            acc[m][n][j] = 0.f;
                        }
                }
            }
        }
    }

    float w1[16], w2[16]; int wid[16];
    #pragma unroll
    for (int sl = 0; sl < 16; ++sl) {
        float a1 = v1[sl]; int ai = id1[sl]; float a2 = v2[sl];
        #pragma unroll
        for (int mk = 1; mk < 16; mk <<= 1) {
            const float o1 = __shfl_xor(a1, mk);
            const int   oi = __shfl_xor(ai, mk);
            const float o2 = __shfl_xor(a2, mk);
            if (o1 < a1)      { a2 = fminf(a1, o2); a1 = o1; ai = oi; }
            else if (o1 > a1) { a2 = fminf(a2, o1); }
            else              { a2 = (oi != ai) ? a1 : fminf(a2, o2); ai = (oi < ai) ? oi : ai; }
        }
        w1[sl] = a1; w2[sl] = a2; wid[sl] = ai;
    }

    __syncthreads();
    float* mv1 = reinterpret_cast<float*>(As);
    float* mv2 = mv1 + 256;
    int*   mid = reinterpret_cast<int*>(mv2 + 256);
    if (col == 0) {
        #pragma unroll
        for (int sl = 0; sl < 16; ++sl) {
            const int m = sl >> 2, j = sl & 3;
            const int p = m * 16 + kg * 4 + j;
            mv1[wv * 64 + p] = w1[sl];
            mv2[wv * 64 + p] = w2[sl];
            mid[wv * 64 + p] = wid[sl];
        }
    }
    __syncthreads();
    if (t < 64) {
        float a1 = mv1[t], a2 = mv2[t]; int ai = mid[t];
        #pragma unroll
        for (int w = 1; w < 4; ++w) {
            const float b1 = mv1[w * 64 + t], b2 = mv2[w * 64 + t];
            const int   bi = mid[w * 64 + t];
            if (b1 < a1)      { a2 = fminf(a1, b2); a1 = b1; ai = bi; }
            else if (b1 > a1) { a2 = fminf(a2, b1); }
            else              { a2 = a1; ai = (bi < ai) ? bi : ai; }
        }
        out_idx[pt0 + t] = ((a2 - a1) <= MARGIN) ? (-1.0f - (float)ai) : (float)ai;
    }
}

// ---------------------------------------------------------------------------
// compact: flagged points -> worklist (order nondeterministic; results are
// per-point independent -> final output deterministic).
// ---------------------------------------------------------------------------
__global__ __launch_bounds__(256)
void vq_compact(const float* __restrict__ idxf, int* __restrict__ cnt,
                int* __restrict__ list)
{
    const int n = blockIdx.x * 256 + threadIdx.x;
    if (idxf[n] < 0.f) { const int p = atomicAdd(cnt, 1); list[p] = n; }
}

// ---------------------------------------------------------------------------
// numpy pairwise-sum replication (verified round 2).
// ---------------------------------------------------------------------------
__device__ __forceinline__ float np_pair128_sq(const float* __restrict__ a) {
    float r[8];
    #pragma unroll
    for (int j = 0; j < 8; ++j) r[j] = __fmul_rn(a[j], a[j]);
    #pragma unroll
    for (int i = 8; i < 128; i += 8)
        #pragma unroll
        for (int j = 0; j < 8; ++j) r[j] = __fadd_rn(r[j], __fmul_rn(a[i + j], a[i + j]));
    const float s01 = __fadd_rn(r[0], r[1]);
    const float s23 = __fadd_rn(r[2], r[3]);
    const float s45 = __fadd_rn(r[4], r[5]);
    const float s67 = __fadd_rn(r[6], r[7]);
    return __fadd_rn(__fadd_rn(s01, s23), __fadd_rn(s45, s67));
}
__device__ __forceinline__ float np_sum256_sq(const float* __restrict__ a) {
    return __fadd_rn(np_pair128_sq(a), np_pair128_sq(a + 128));
}

// ---------------------------------------------------------------------------
// fixup2: one block per flagged point (grid-stride over worklist).
// emb staged in LDS 32 codes/tile (coalesced float4, stride-264 rows);
// per code an 8-lane group maps numpy's 8 pairwise chains 1:1 to lanes and
// merges with an fadd xor-butterfly (IEEE add commutative == numpy's tree).
// dot in f64 (32 fma/lane). Replicates np f32 binning exactly.
// ---------------------------------------------------------------------------
__global__ __launch_bounds__(256)
void vq_fixup2(const float* __restrict__ z, const float* __restrict__ emb,
               float* __restrict__ idxf, const int* __restrict__ cnt,
               const int* __restrict__ list)
{
    __shared__ float zs[ZC];
    __shared__ float es[32 * 264];
    __shared__ float gbv[32];
    __shared__ int   gbk[32];

    const int t = threadIdx.x;
    const int g = t >> 3, r = t & 7;
    const int C = *cnt;

    for (int it = blockIdx.x; it < C; it += 512) {
        const int n = list[it];
        const int b = n >> 10, q = n & 1023;
        __syncthreads();
        zs[t] = z[(size_t)b * (ZC * 1024) + (size_t)t * 1024 + q];
        __syncthreads();

        const float zn = np_sum256_sq(zs);   // per-thread redundant; broadcast LDS reads

        float best = 3.4e38f; int bestk = 0x7fffffff;

        for (int tile = 0; tile < 32; ++tile) {
            __syncthreads();
            const float4* src = reinterpret_cast<const float4*>(emb + (size_t)tile * 32 * ZC);
            #pragma unroll
            for (int i = 0; i < 8; ++i) {
                const int f = i * 256 + t;
                const int row = f >> 6, c4 = f & 63;
                *reinterpret_cast<float4*>(es + row * 264 + c4 * 4) = src[f];
            }
            __syncthreads();

            const float* er = es + g * 264;
            float lo, hi;
            double dd;
            {
                const float a0 = er[r];
                const float a1 = er[128 + r];
                lo = __fmul_rn(a0, a0);
                hi = __fmul_rn(a1, a1);
                dd = fma((double)a0, (double)zs[r],
                     fma((double)a1, (double)zs[128 + r], 0.0));
            }
            #pragma unroll
            for (int i = 1; i < 16; ++i) {
                const int c = 8 * i + r;
                const float a0 = er[c];
                const float a1 = er[128 + c];
                lo = __fadd_rn(lo, __fmul_rn(a0, a0));
                hi = __fadd_rn(hi, __fmul_rn(a1, a1));
                dd = fma((double)a0, (double)zs[c], dd);
                dd = fma((double)a1, (double)zs[128 + c], dd);
            }
            #pragma unroll
            for (int mk = 1; mk < 8; mk <<= 1) {
                lo = __fadd_rn(lo, __shfl_xor(lo, mk));
                hi = __fadd_rn(hi, __shfl_xor(hi, mk));
                dd = dd + __shfl_xor(dd, mk);
            }
            if (r == 0) {
                const float en  = __fadd_rn(lo, hi);
                const float t2f = (float)dd;
                const float d   = __fsub_rn(__fadd_rn(zn, en), __fmul_rn(2.0f, t2f));
                const int code  = tile * 32 + g;
                if (d < best) { best = d; bestk = code; }   // codes ascending per group
            }
        }

        if (r == 0) { gbv[g] = best; gbk[g] = bestk; }
        __syncthreads();
        if (t == 0) {
            float bv = gbv[0]; int bk = gbk[0];
            for (int gg = 1; gg < 32; ++gg)
                if (gbv[gg] < bv || (gbv[gg] == bv && gbk[gg] < bk)) { bv = gbv[gg]; bk = gbk[gg]; }
            idxf[n] = (float)bk;
        }
        __syncthreads();
    }
}

// ---------------------------------------------------------------------------
// outputs (verified round 2, unchanged) — overwrites the scratch regions.
// ---------------------------------------------------------------------------
__global__ __launch_bounds__(256)
void vq_outputs_kernel(const float* __restrict__ z, const float* __restrict__ emb,
                       const float* __restrict__ idxf,
                       float* __restrict__ out_q, float* __restrict__ out_loss)
{
    __shared__ float zts[32 * 257];
    __shared__ int   ids[32];

    const int t  = threadIdx.x;
    const int bh = blockIdx.x;
    const int b  = bh >> 5, h = bh & 31;
    const int n0 = bh * 32;

    if (t < 32) ids[t] = (int)idxf[n0 + t];
    __syncthreads();

    const size_t zbase = (size_t)b * (ZC * 1024) + h * 32;

    for (int rep = 0; rep < 32; ++rep) {
        const int flat = rep * 256 + t;
        const int c = flat >> 5;
        const int ww = flat & 31;
        const size_t ga = zbase + (size_t)c * 1024 + ww;
        const float zv = z[ga];
        zts[ww * 257 + c] = zv;
        out_q[ga] = emb[(size_t)ids[ww] * ZC + c];
    }
    __syncthreads();

    for (int rep = 0; rep < 32; ++rep) {
        const float e = emb[(size_t)ids[rep] * ZC + t];
        const float d = e - zts[rep * 257 + t];
        out_loss[(size_t)(n0 + rep) * ZC + t] = 1.25f * d * d;
    }
}

extern "C" void kernel_launch(void* const* d_in, const int* in_sizes, int n_in,
                              void* d_out, int out_size, void* d_ws, size_t ws_size,
                              hipStream_t stream)
{
    const float* z   = (const float*)d_in[0];   // [32,256,32,32]
    const float* emb = (const float*)d_in[1];   // [1024,256]
    float* out      = (float*)d_out;
    float* out_q    = out;                       // 8388608 floats
    float* out_loss = out + 8388608;             // 8388608 floats
    float* out_idx  = out + 16777216;            // 32768 floats

    // scratch carved from output regions (fully overwritten by final kernels):
    unsigned short* Ab = (unsigned short*)d_out;                       // 32 MiB (out_q)
    unsigned short* Bb = (unsigned short*)((char*)d_out + 33554432);   // 1 MiB
    float* ensg = (float*)((char*)d_out + 34603008);                   // 4 KiB
    int*   cnt  = (int*)  ((char*)d_out + 34607104);                   // 4 B
    int*   list = (int*)  ((char*)d_out + 34607168);                   // 128 KiB max

    vq_prep_z        <<<4096, 256, 0, stream>>>(z, Ab);
    vq_prep_e        <<<128,  256, 0, stream>>>(emb, Bb);
    vq_ens           <<<16,   256, 0, stream>>>(emb, ensg, cnt);
    vq_gemm_argmin   <<<512,  256, 0, stream>>>(Ab, Bb, ensg, out_idx);
    vq_compact       <<<128,  256, 0, stream>>>(out_idx, cnt, list);
    vq_fixup2        <<<512,  256, 0, stream>>>(z, emb, out_idx, cnt, list);
    vq_outputs_kernel<<<1024, 256, 0, stream>>>(z, emb, out_idx, out_q, out_loss);
}

// Round 7
// 255.891 us; speedup vs baseline: 2.3725x; 1.0986x over previous
//
#include <hip/hip_runtime.h>

#define ZC     256
#define KCODES 1024
#define MARGIN 1e-4f

typedef __attribute__((ext_vector_type(4))) float f32x4;
typedef __attribute__((ext_vector_type(8))) short s16x8;
typedef unsigned int u32t;
typedef u32t __attribute__((address_space(1))) as1_u32;
typedef u32t __attribute__((address_space(3))) as3_u32;

__device__ __forceinline__ void glds16(const void* g, void* l) {
    __builtin_amdgcn_global_load_lds((const as1_u32*)g, (as3_u32*)l, 16, 0, 0);
}
__device__ __forceinline__ unsigned short bf16_rn(float x) {
    union { float f; u32t u; } v; v.f = x;
    return (unsigned short)((v.u + 0x7FFFu + ((v.u >> 16) & 1u)) >> 16);
}
__device__ __forceinline__ float bf16_f(unsigned short h) {
    union { u32t u; float f; } v; v.u = ((u32t)h) << 16; return v.f;
}

// ---------------------------------------------------------------------------
// prep_z: z fp32 [32,256,32,32] -> A' bf16 [8 kblk][32768 pt][64 k], with the
// LDS XOR-swizzle PRE-BAKED into the global layout (rule #21: swizzle source +
// read, keep glds dest linear): short col = k ^ ((pt&7)<<3)  (16B granules).
// kblk 0-3 = hi (c 0..255), kblk 4-7 = lo residual.
// ---------------------------------------------------------------------------
__global__ __launch_bounds__(256)
void vq_prep_z(const float* __restrict__ z, unsigned short* __restrict__ Ab)
{
    const int t = threadIdx.x, blk = blockIdx.x;
    const int pt = (blk >> 3) * 64 + (t & 63);
    const int c0 = (blk & 7) * 32 + (t >> 6) * 8;
    const int b = pt >> 10, hw = pt & 1023;
    const float* zp = z + (size_t)b * (ZC * 1024) + (size_t)c0 * 1024 + hw;

    unsigned short hi[8], lo[8];
    #pragma unroll
    for (int j = 0; j < 8; ++j) {
        const float v = zp[(size_t)j * 1024];
        const unsigned short h = bf16_rn(v);
        hi[j] = h; lo[j] = bf16_rn(v - bf16_f(h));
    }
    uint4 ph, pl;
    ph.x = (u32t)hi[0] | ((u32t)hi[1] << 16); ph.y = (u32t)hi[2] | ((u32t)hi[3] << 16);
    ph.z = (u32t)hi[4] | ((u32t)hi[5] << 16); ph.w = (u32t)hi[6] | ((u32t)hi[7] << 16);
    pl.x = (u32t)lo[0] | ((u32t)lo[1] << 16); pl.y = (u32t)lo[2] | ((u32t)lo[3] << 16);
    pl.z = (u32t)lo[4] | ((u32t)lo[5] << 16); pl.w = (u32t)lo[6] | ((u32t)lo[7] << 16);

    const size_t kbH = (size_t)(c0 >> 6), kbL = kbH + 4;
    const int sw = (c0 & 63) ^ ((pt & 7) << 3);          // swizzled 8-short granule
    const size_t base = (size_t)pt * 64 + sw;
    *reinterpret_cast<uint4*>(Ab + kbH * (32768ull * 64) + base) = ph;
    *reinterpret_cast<uint4*>(Ab + kbL * (32768ull * 64) + base) = pl;
}

// ---------------------------------------------------------------------------
// prep_e: emb fp32 [1024,256] -> B' bf16 [8 kblk][1024 code][64], same baked
// swizzle: short col = k ^ ((code&7)<<3).
// ---------------------------------------------------------------------------
__global__ __launch_bounds__(256)
void vq_prep_e(const float* __restrict__ emb, unsigned short* __restrict__ Bb)
{
    const int t = threadIdx.x, blk = blockIdx.x;
    const int code = (blk >> 3) * 64 + (t & 63);
    const int c0 = (blk & 7) * 32 + (t >> 6) * 8;
    const float* ep = emb + (size_t)code * ZC + c0;

    unsigned short hi[8], lo[8];
    #pragma unroll
    for (int j = 0; j < 8; ++j) {
        const float v = ep[j];
        const unsigned short h = bf16_rn(v);
        hi[j] = h; lo[j] = bf16_rn(v - bf16_f(h));
    }
    uint4 ph, pl;
    ph.x = (u32t)hi[0] | ((u32t)hi[1] << 16); ph.y = (u32t)hi[2] | ((u32t)hi[3] << 16);
    ph.z = (u32t)hi[4] | ((u32t)hi[5] << 16); ph.w = (u32t)hi[6] | ((u32t)hi[7] << 16);
    pl.x = (u32t)lo[0] | ((u32t)lo[1] << 16); pl.y = (u32t)lo[2] | ((u32t)lo[3] << 16);
    pl.z = (u32t)lo[4] | ((u32t)lo[5] << 16); pl.w = (u32t)lo[6] | ((u32t)lo[7] << 16);

    const size_t kbH = (size_t)(c0 >> 6), kbL = kbH + 4;
    const int sw = (c0 & 63) ^ ((code & 7) << 3);
    const size_t base = (size_t)code * 64 + sw;
    *reinterpret_cast<uint4*>(Bb + kbH * (1024ull * 64) + base) = ph;
    *reinterpret_cast<uint4*>(Bb + kbL * (1024ull * 64) + base) = pl;
}

// ---------------------------------------------------------------------------
// ens: codebook squared norms (fp32) -> ens_g[1024]; zeroes fixup counter.
// ---------------------------------------------------------------------------
__global__ __launch_bounds__(256)
void vq_ens(const float* __restrict__ emb, float* __restrict__ ens_g,
            int* __restrict__ cnt)
{
    if (blockIdx.x == 0 && threadIdx.x == 0) *cnt = 0;
    const int t = threadIdx.x, lane = t & 63, w = t >> 6;
    for (int rep = 0; rep < 16; ++rep) {
        const int k = blockIdx.x * 64 + rep * 4 + w;
        const float4 v = *reinterpret_cast<const float4*>(emb + (size_t)k * ZC + lane * 4);
        float s = v.x * v.x + v.y * v.y + v.z * v.z + v.w * v.w;
        #pragma unroll
        for (int m = 1; m < 64; m <<= 1) s += __shfl_xor(s, m);
        if (lane == 0) ens_g[k] = s;
    }
}

// ---------------------------------------------------------------------------
// GEMM+argmin: geometry and reduction IDENTICAL to verified round 6; only the
// staging changed: global_load_lds width-16 into LINEAR LDS (swizzle is baked
// in the global layout), ds_read applies the matching XOR.
// ---------------------------------------------------------------------------
__global__ __launch_bounds__(256, 2)
void vq_gemm_argmin(const unsigned short* __restrict__ Ab,
                    const unsigned short* __restrict__ Bb,
                    const float* __restrict__ ens_g, float* __restrict__ out_idx)
{
    __shared__ unsigned short As[64 * 64];     // 8 KB, linear (glds dest)
    __shared__ unsigned short Bs[128 * 64];    // 16 KB, linear

    const int t = threadIdx.x;
    const int lane = t & 63, wv = t >> 6;
    const int col = lane & 15, kg = lane >> 4;
    const int pt0 = blockIdx.x * 64;
    const int kx = (col & 7) << 3;             // read-side XOR (shorts)

    int aoff[4][2], boff[2][2];                // offsets in shorts
    #pragma unroll
    for (int m = 0; m < 4; ++m)
        #pragma unroll
        for (int s = 0; s < 2; ++s)
            aoff[m][s] = (m * 16 + col) * 64 + ((s * 32 + kg * 8) ^ kx);
    #pragma unroll
    for (int n = 0; n < 2; ++n)
        #pragma unroll
        for (int s = 0; s < 2; ++s)
            boff[n][s] = (wv * 32 + n * 16 + col) * 64 + ((s * 32 + kg * 8) ^ kx);

    f32x4 acc[4][2];
    #pragma unroll
    for (int m = 0; m < 4; ++m)
        #pragma unroll
        for (int n = 0; n < 2; ++n) acc[m][n] = (f32x4){0.f, 0.f, 0.f, 0.f};

    float v1[16], v2[16]; int id1[16];
    #pragma unroll
    for (int i = 0; i < 16; ++i) { v1[i] = 3.4e38f; v2[i] = 3.4e38f; id1[i] = 0; }

    for (int ct = 0; ct < 8; ++ct) {
        for (int ks = 0; ks < 12; ++ks) {
            const int kbA = (((ks >> 2) == 1) ? 4 : 0) + (ks & 3);
            const int kbB = (((ks >> 2) == 2) ? 4 : 0) + (ks & 3);
            const char* aS = (const char*)(Ab + (size_t)kbA * (32768ull * 64) + (size_t)pt0 * 64);
            const char* bS = (const char*)(Bb + (size_t)kbB * (1024ull * 64)  + (size_t)ct * (128 * 64));

            __syncthreads();   // prior k-step's LDS reads complete
            glds16(aS + t * 16,        (char*)As + t * 16);
            glds16(aS + 4096 + t * 16, (char*)As + 4096 + t * 16);
            #pragma unroll
            for (int q = 0; q < 4; ++q)
                glds16(bS + q * 4096 + t * 16, (char*)Bs + q * 4096 + t * 16);
            __syncthreads();   // compiler drains vmcnt before barrier

            s16x8 af[4][2], bf[2][2];
            #pragma unroll
            for (int m = 0; m < 4; ++m)
                #pragma unroll
                for (int s = 0; s < 2; ++s)
                    af[m][s] = *reinterpret_cast<const s16x8*>(As + aoff[m][s]);
            #pragma unroll
            for (int n = 0; n < 2; ++n)
                #pragma unroll
                for (int s = 0; s < 2; ++s)
                    bf[n][s] = *reinterpret_cast<const s16x8*>(Bs + boff[n][s]);
            #pragma unroll
            for (int m = 0; m < 4; ++m)
                #pragma unroll
                for (int n = 0; n < 2; ++n) {
                    acc[m][n] = __builtin_amdgcn_mfma_f32_16x16x32_bf16(af[m][0], bf[n][0], acc[m][n], 0, 0, 0);
                    acc[m][n] = __builtin_amdgcn_mfma_f32_16x16x32_bf16(af[m][1], bf[n][1], acc[m][n], 0, 0, 0);
                }

            if (ks == 11) {
                #pragma unroll
                for (int n = 0; n < 2; ++n) {
                    const int code = ct * 128 + wv * 32 + n * 16 + col;
                    const float en = ens_g[code];
                    #pragma unroll
                    for (int m = 0; m < 4; ++m)
                        #pragma unroll
                        for (int j = 0; j < 4; ++j) {
                            const float sc = fmaf(-2.f, acc[m][n][j], en);
                            const int sl = m * 4 + j;
                            if (sc < v1[sl]) { v2[sl] = v1[sl]; v1[sl] = sc; id1[sl] = code; }
                            else if (sc < v2[sl]) { v2[sl] = sc; }
                            acc[m][n][j] = 0.f;
                        }
                }
            }
        }
    }

    // in-wave 16-lane top-2 merge (verified round 5/6)
    float w1[16], w2[16]; int wid[16];
    #pragma unroll
    for (int sl = 0; sl < 16; ++sl) {
        float a1 = v1[sl]; int ai = id1[sl]; float a2 = v2[sl];
        #pragma unroll
        for (int mk = 1; mk < 16; mk <<= 1) {
            const float o1 = __shfl_xor(a1, mk);
            const int   oi = __shfl_xor(ai, mk);
            const float o2 = __shfl_xor(a2, mk);
            if (o1 < a1)      { a2 = fminf(a1, o2); a1 = o1; ai = oi; }
            else if (o1 > a1) { a2 = fminf(a2, o1); }
            else              { a2 = (oi != ai) ? a1 : fminf(a2, o2); ai = (oi < ai) ? oi : ai; }
        }
        w1[sl] = a1; w2[sl] = a2; wid[sl] = ai;
    }

    // cross-wave merge via LDS (verified round 5/6)
    __syncthreads();
    float* mv1 = reinterpret_cast<float*>(As);
    float* mv2 = mv1 + 256;
    int*   mid = reinterpret_cast<int*>(mv2 + 256);
    if (col == 0) {
        #pragma unroll
        for (int sl = 0; sl < 16; ++sl) {
            const int m = sl >> 2, j = sl & 3;
            const int p = m * 16 + kg * 4 + j;
            mv1[wv * 64 + p] = w1[sl];
            mv2[wv * 64 + p] = w2[sl];
            mid[wv * 64 + p] = wid[sl];
        }
    }
    __syncthreads();
    if (t < 64) {
        float a1 = mv1[t], a2 = mv2[t]; int ai = mid[t];
        #pragma unroll
        for (int w = 1; w < 4; ++w) {
            const float b1 = mv1[w * 64 + t], b2 = mv2[w * 64 + t];
            const int   bi = mid[w * 64 + t];
            if (b1 < a1)      { a2 = fminf(a1, b2); a1 = b1; ai = bi; }
            else if (b1 > a1) { a2 = fminf(a2, b1); }
            else              { a2 = a1; ai = (bi < ai) ? bi : ai; }
        }
        out_idx[pt0 + t] = ((a2 - a1) <= MARGIN) ? (-1.0f - (float)ai) : (float)ai;
    }
}

// ---------------------------------------------------------------------------
// compact: flagged points -> worklist.
// ---------------------------------------------------------------------------
__global__ __launch_bounds__(256)
void vq_compact(const float* __restrict__ idxf, int* __restrict__ cnt,
                int* __restrict__ list)
{
    const int n = blockIdx.x * 256 + threadIdx.x;
    if (idxf[n] < 0.f) { const int p = atomicAdd(cnt, 1); list[p] = n; }
}

// ---------------------------------------------------------------------------
// numpy pairwise-sum replication (verified round 2).
// ---------------------------------------------------------------------------
__device__ __forceinline__ float np_pair128_sq(const float* __restrict__ a) {
    float r[8];
    #pragma unroll
    for (int j = 0; j < 8; ++j) r[j] = __fmul_rn(a[j], a[j]);
    #pragma unroll
    for (int i = 8; i < 128; i += 8)
        #pragma unroll
        for (int j = 0; j < 8; ++j) r[j] = __fadd_rn(r[j], __fmul_rn(a[i + j], a[i + j]));
    const float s01 = __fadd_rn(r[0], r[1]);
    const float s23 = __fadd_rn(r[2], r[3]);
    const float s45 = __fadd_rn(r[4], r[5]);
    const float s67 = __fadd_rn(r[6], r[7]);
    return __fadd_rn(__fadd_rn(s01, s23), __fadd_rn(s45, s67));
}
__device__ __forceinline__ float np_sum256_sq(const float* __restrict__ a) {
    return __fadd_rn(np_pair128_sq(a), np_pair128_sq(a + 128));
}

// ---------------------------------------------------------------------------
// fixup2 (verified round 6): one block per flagged point, np-exact adjudication.
// ---------------------------------------------------------------------------
__global__ __launch_bounds__(256)
void vq_fixup2(const float* __restrict__ z, const float* __restrict__ emb,
               float* __restrict__ idxf, const int* __restrict__ cnt,
               const int* __restrict__ list)
{
    __shared__ float zs[ZC];
    __shared__ float es[32 * 264];
    __shared__ float gbv[32];
    __shared__ int   gbk[32];

    const int t = threadIdx.x;
    const int g = t >> 3, r = t & 7;
    const int C = *cnt;

    for (int it = blockIdx.x; it < C; it += 512) {
        const int n = list[it];
        const int b = n >> 10, q = n & 1023;
        __syncthreads();
        zs[t] = z[(size_t)b * (ZC * 1024) + (size_t)t * 1024 + q];
        __syncthreads();

        const float zn = np_sum256_sq(zs);

        float best = 3.4e38f; int bestk = 0x7fffffff;

        for (int tile = 0; tile < 32; ++tile) {
            __syncthreads();
            const float4* src = reinterpret_cast<const float4*>(emb + (size_t)tile * 32 * ZC);
            #pragma unroll
            for (int i = 0; i < 8; ++i) {
                const int f = i * 256 + t;
                const int row = f >> 6, c4 = f & 63;
                *reinterpret_cast<float4*>(es + row * 264 + c4 * 4) = src[f];
            }
            __syncthreads();

            const float* er = es + g * 264;
            float lo, hi;
            double dd;
            {
                const float a0 = er[r];
                const float a1 = er[128 + r];
                lo = __fmul_rn(a0, a0);
                hi = __fmul_rn(a1, a1);
                dd = fma((double)a0, (double)zs[r],
                     fma((double)a1, (double)zs[128 + r], 0.0));
            }
            #pragma unroll
            for (int i = 1; i < 16; ++i) {
                const int c = 8 * i + r;
                const float a0 = er[c];
                const float a1 = er[128 + c];
                lo = __fadd_rn(lo, __fmul_rn(a0, a0));
                hi = __fadd_rn(hi, __fmul_rn(a1, a1));
                dd = fma((double)a0, (double)zs[c], dd);
                dd = fma((double)a1, (double)zs[128 + c], dd);
            }
            #pragma unroll
            for (int mk = 1; mk < 8; mk <<= 1) {
                lo = __fadd_rn(lo, __shfl_xor(lo, mk));
                hi = __fadd_rn(hi, __shfl_xor(hi, mk));
                dd = dd + __shfl_xor(dd, mk);
            }
            if (r == 0) {
                const float en  = __fadd_rn(lo, hi);
                const float t2f = (float)dd;
                const float d   = __fsub_rn(__fadd_rn(zn, en), __fmul_rn(2.0f, t2f));
                const int code  = tile * 32 + g;
                if (d < best) { best = d; bestk = code; }
            }
        }

        if (r == 0) { gbv[g] = best; gbk[g] = bestk; }
        __syncthreads();
        if (t == 0) {
            float bv = gbv[0]; int bk = gbk[0];
            for (int gg = 1; gg < 32; ++gg)
                if (gbv[gg] < bv || (gbv[gg] == bv && gbk[gg] < bk)) { bv = gbv[gg]; bk = gbk[gg]; }
            idxf[n] = (float)bk;
        }
        __syncthreads();
    }
}

// ---------------------------------------------------------------------------
// outputs (verified round 2) — overwrites the scratch regions.
// ---------------------------------------------------------------------------
__global__ __launch_bounds__(256)
void vq_outputs_kernel(const float* __restrict__ z, const float* __restrict__ emb,
                       const float* __restrict__ idxf,
                       float* __restrict__ out_q, float* __restrict__ out_loss)
{
    __shared__ float zts[32 * 257];
    __shared__ int   ids[32];

    const int t  = threadIdx.x;
    const int bh = blockIdx.x;
    const int b  = bh >> 5, h = bh & 31;
    const int n0 = bh * 32;

    if (t < 32) ids[t] = (int)idxf[n0 + t];
    __syncthreads();

    const size_t zbase = (size_t)b * (ZC * 1024) + h * 32;

    for (int rep = 0; rep < 32; ++rep) {
        const int flat = rep * 256 + t;
        const int c = flat >> 5;
        const int ww = flat & 31;
        const size_t ga = zbase + (size_t)c * 1024 + ww;
        const float zv = z[ga];
        zts[ww * 257 + c] = zv;
        out_q[ga] = emb[(size_t)ids[ww] * ZC + c];
    }
    __syncthreads();

    for (int rep = 0; rep < 32; ++rep) {
        const float e = emb[(size_t)ids[rep] * ZC + t];
        const float d = e - zts[rep * 257 + t];
        out_loss[(size_t)(n0 + rep) * ZC + t] = 1.25f * d * d;
    }
}

extern "C" void kernel_launch(void* const* d_in, const int* in_sizes, int n_in,
                              void* d_out, int out_size, void* d_ws, size_t ws_size,
                              hipStream_t stream)
{
    const float* z   = (const float*)d_in[0];   // [32,256,32,32]
    const float* emb = (const float*)d_in[1];   // [1024,256]
    float* out      = (float*)d_out;
    float* out_q    = out;                       // 8388608 floats
    float* out_loss = out + 8388608;             // 8388608 floats
    float* out_idx  = out + 16777216;            // 32768 floats

    // scratch carved from output regions (fully overwritten by final kernels):
    unsigned short* Ab = (unsigned short*)d_out;                       // 32 MiB (out_q)
    unsigned short* Bb = (unsigned short*)((char*)d_out + 33554432);   // 1 MiB
    float* ensg = (float*)((char*)d_out + 34603008);                   // 4 KiB
    int*   cnt  = (int*)  ((char*)d_out + 34607104);                   // 4 B
    int*   list = (int*)  ((char*)d_out + 34607168);                   // 128 KiB max

    vq_prep_z        <<<4096, 256, 0, stream>>>(z, Ab);
    vq_prep_e        <<<128,  256, 0, stream>>>(emb, Bb);
    vq_ens           <<<16,   256, 0, stream>>>(emb, ensg, cnt);
    vq_gemm_argmin   <<<512,  256, 0, stream>>>(Ab, Bb, ensg, out_idx);
    vq_compact       <<<128,  256, 0, stream>>>(out_idx, cnt, list);
    vq_fixup2        <<<512,  256, 0, stream>>>(z, emb, out_idx, cnt, list);
    vq_outputs_kernel<<<1024, 256, 0, stream>>>(z, emb, out_idx, out_q, out_loss);
}